// Round 1
// 220.862 us; speedup vs baseline: 1.0004x; 1.0004x over previous
//
#include <hip/hip_runtime.h>
#include <stdint.h>

// Problem constants (fixed by the reference):
#define N_ROWS 262144
#define DIM    128
#define HID    16
#define NEXP   21
// Segments of 64 rows, each expert's region padded up to a multiple of 64.
#define NSEG   (N_ROWS / 64 + NEXP)   // 4096 + 21 = 4117 worst case
#define NBLK1  256                    // blocks for hist/scatter
#define RPB    (N_ROWS / NBLK1)       // 1024 rows per block
#define RPT    (RPB / 256)            // 4 rows per thread

// ---------------------------------------------------------------------------
// K1: per-block histogram of sid + reserve per-(block,expert) ranges.
// ---------------------------------------------------------------------------
__global__ __launch_bounds__(256) void k_hist(const int* __restrict__ sid,
                                              int* __restrict__ counts,
                                              int* __restrict__ blockBase) {
    __shared__ int lh[NEXP];
    int t = threadIdx.x;
    if (t < NEXP) lh[t] = 0;
    __syncthreads();
    int base = blockIdx.x * RPB + t;
#pragma unroll
    for (int r = 0; r < RPT; r++) {
        atomicAdd(&lh[sid[base + r * 256]], 1);
    }
    __syncthreads();
    if (t < NEXP) blockBase[blockIdx.x * NEXP + t] = atomicAdd(&counts[t], lh[t]);
}

// ---------------------------------------------------------------------------
// K2: scatter rows into per-expert 64-padded buckets.  Entry = row | (e<<24).
// Tail slots stay -1 (memset 0xFF).
// ---------------------------------------------------------------------------
__global__ __launch_bounds__(256) void k_scatter(const int* __restrict__ sid,
                                                 const int* __restrict__ counts,
                                                 const int* __restrict__ blockBase,
                                                 int* __restrict__ buckets) {
    __shared__ int sbase[NEXP];
    __shared__ int lcur[NEXP];
    int t = threadIdx.x;
    if (t == 0) {
        int acc = 0;
        for (int e = 0; e < NEXP; e++) {
            sbase[e] = acc + blockBase[blockIdx.x * NEXP + e];
            acc += ((counts[e] + 63) >> 6) << 6;   // pad each expert to 64
        }
    }
    if (t < NEXP) lcur[t] = 0;
    __syncthreads();
    int base = blockIdx.x * RPB + t;
#pragma unroll
    for (int r = 0; r < RPT; r++) {
        int row = base + r * 256;
        int e = sid[row];
        int lp = atomicAdd(&lcur[e], 1);
        buckets[sbase[e] + lp] = row | (e << 24);
    }
}

// ---------------------------------------------------------------------------
// K3 (round 6): MFMA rewrite.
//
// History: r1-r5 established the VALU path's ceiling.  r5 (readlane W1
// broadcast + LDS-staged x, 221 us total) still executed 2048 v_fmac + 2048
// v_readlane per lane plus a full s_waitcnt-0 drain per phase: VALU+drain
// bound at ~3x the 21-us HBM floor of the 134 MB x stream.
//
// r6 observation: each 64-row segment is X[64x128] @ W1[128x16] -- MFMA
// shaped.  No fp32 MFMA on CDNA4, but the all-fp32 kernel already measures
// absmax 0.00195 vs the JAX reference, so split-bf16 (hi+lo, 3 products,
// fp32 accumulate, ~16 mantissa bits, error ~2e-4) is safely inside
// tolerance.  Per wave: 48 v_mfma_f32_16x16x32_bf16 + ~600 VALU of
// convert/pack replace the 4096-inst VALU stream; A-fragments are loaded
// straight from global (lane = row l&15, k = (l>>4)*8+e  =>  8 consecutive
// floats/lane; the wave consumes whole 128-B lines), so LDS, staging and
// the per-phase drains disappear entirely.  Expected k_main ~25-30 us,
// HBM-bound.
// ---------------------------------------------------------------------------
typedef __attribute__((ext_vector_type(8))) short bf16x8;   // 8 bf16 = 4 VGPR
typedef __attribute__((ext_vector_type(4))) float f32x4;

// dst = { hi16(a) , hi16(b) }  (bf16 truncation of two fp32, packed)
__device__ __forceinline__ uint32_t pack2(uint32_t a, uint32_t b) {
    return __builtin_amdgcn_perm(b, a, 0x07060302u);  // bytes: b3 b2 a3 a2
}

// 8 fp32 -> hi-frag (bf16 trunc) + lo-frag (bf16 trunc of residual)
__device__ __forceinline__ void cvt8(const float* f, bf16x8& fh, bf16x8& fl) {
    union { uint32_t u[4]; bf16x8 v; } H, L;
#pragma unroll
    for (int i = 0; i < 4; i++) {
        uint32_t a = __float_as_uint(f[2 * i]);
        uint32_t b = __float_as_uint(f[2 * i + 1]);
        H.u[i] = pack2(a, b);
        float ra = f[2 * i]     - __uint_as_float(a & 0xffff0000u);
        float rb = f[2 * i + 1] - __uint_as_float(b & 0xffff0000u);
        L.u[i] = pack2(__float_as_uint(ra), __float_as_uint(rb));
    }
    fh = H.v; fl = L.v;
}

__global__ __launch_bounds__(256, 4) void k_mfma(const float* __restrict__ x,
                                                 const float* __restrict__ W1,
                                                 const float* __restrict__ b1,
                                                 const float* __restrict__ W2,
                                                 const float* __restrict__ b2,
                                                 const int* __restrict__ buckets,
                                                 float* __restrict__ out) {
    const int seg = blockIdx.x * 4 + (threadIdx.x >> 6);
    if (seg >= NSEG) return;                       // wave-uniform
    const int lane = threadIdx.x & 63;

    const int ent = buckets[seg * 64 + lane];
    if (__ballot(ent >= 0) == 0ULL) return;        // wholly-empty tail segment
    // Valid slots form a prefix -> lane 0 valid -> e is wave-uniform.
    const int e = __builtin_amdgcn_readfirstlane(ent) >> 24;
    const int row0 = __shfl(ent, 0, 64) & 0x00FFFFFF;
    const int vrow = (ent >= 0) ? (ent & 0x00FFFFFF) : row0;  // pad lanes dup row0

    const int ncol  = lane & 15;        // A-row within tile / B,D column
    const int kbase = (lane >> 4) * 8;  // this lane's k offset within a K=32 step

    // Row each lane loads for A-tile mt: slot mt*16 + ncol.
    int arow[4];
#pragma unroll
    for (int mt = 0; mt < 4; mt++) arow[mt] = __shfl(vrow, mt * 16 + ncol, 64);

    const float* __restrict__ w1 = W1 + e * (DIM * HID);
    // Tiny per-lane epilogue constants (L2-hot); issue early.
    const float b1v = b1[e * HID + ncol];
    const float w2v = W2[e * HID + ncol];
    const float b2v = b2[e];

    const f32x4 zero = {0.0f, 0.0f, 0.0f, 0.0f};
    f32x4 acc[4] = {zero, zero, zero, zero};       // 4 M-tiles of 16 rows

#pragma unroll 1
    for (int kt = 0; kt < 4; kt++) {               // K = 128 = 4 steps of 32
        // ---- B fragment (W1[k][n]): lane holds k = kt*32+kbase+t, n = ncol ----
        float bf[8];
        const float* wp = w1 + (kt * 32 + kbase) * HID + ncol;
#pragma unroll
        for (int t = 0; t < 8; t++) bf[t] = wp[t * HID];
        bf16x8 bh, bl;
        cvt8(bf, bh, bl);

#pragma unroll
        for (int mt = 0; mt < 4; mt++) {
            // ---- A fragment: 8 consecutive floats of row arow[mt] ----
            const float* xp = x + (size_t)arow[mt] * DIM + kt * 32 + kbase;
            float af[8];
            *(float4*)(af)     = *(const float4*)(xp);
            *(float4*)(af + 4) = *(const float4*)(xp + 4);
            bf16x8 ah, al;
            cvt8(af, ah, al);
            // hi*hi + lo*hi + hi*lo  (lo*lo ~2^-16 relative: dropped)
            acc[mt] = __builtin_amdgcn_mfma_f32_16x16x32_bf16(ah, bh, acc[mt], 0, 0, 0);
            acc[mt] = __builtin_amdgcn_mfma_f32_16x16x32_bf16(al, bh, acc[mt], 0, 0, 0);
            acc[mt] = __builtin_amdgcn_mfma_f32_16x16x32_bf16(ah, bl, acc[mt], 0, 0, 0);
        }
    }

    // Epilogue: D[row = mt*16 + (lane>>4)*4 + r][col = ncol] in acc[mt][r].
    // h = relu(D + b1[col]); y = relu(sum_col h*W2[col] + b2) -> 16-lane reduce.
#pragma unroll
    for (int mt = 0; mt < 4; mt++) {
#pragma unroll
        for (int r = 0; r < 4; r++) {
            float c = fmaxf(acc[mt][r] + b1v, 0.0f) * w2v;
            c += __shfl_xor(c, 1, 64);
            c += __shfl_xor(c, 2, 64);
            c += __shfl_xor(c, 4, 64);
            c += __shfl_xor(c, 8, 64);
            const int slot = mt * 16 + (lane >> 4) * 4 + r;
            const int sent = __shfl(ent, slot, 64);
            if (ncol == 0 && sent >= 0)
                out[sent & 0x00FFFFFF] = fmaxf(c + b2v, 0.0f);
        }
    }
}

// ---------------------------------------------------------------------------
// Fallback (only if ws_size is too small for the buckets): thread-per-row.
// ---------------------------------------------------------------------------
__global__ __launch_bounds__(256) void k_naive(const float* __restrict__ x,
                                               const int* __restrict__ sid,
                                               const float* __restrict__ W1,
                                               const float* __restrict__ b1,
                                               const float* __restrict__ W2,
                                               const float* __restrict__ b2,
                                               float* __restrict__ out) {
    int row = blockIdx.x * 256 + threadIdx.x;
    if (row >= N_ROWS) return;
    int e = sid[row];
    const float* w1 = W1 + e * (DIM * HID);
    const float* xr = x + (size_t)row * DIM;
    float h[HID];
#pragma unroll
    for (int j = 0; j < HID; j++) h[j] = b1[e * HID + j];
    for (int k = 0; k < DIM; k++) {
        float xk = xr[k];
#pragma unroll
        for (int j = 0; j < HID; j++) h[j] = fmaf(xk, w1[k * HID + j], h[j]);
    }
    float acc = b2[e];
#pragma unroll
    for (int j = 0; j < HID; j++) acc = fmaf(fmaxf(h[j], 0.0f), W2[e * HID + j], acc);
    out[row] = fmaxf(acc, 0.0f);
}

extern "C" void kernel_launch(void* const* d_in, const int* in_sizes, int n_in,
                              void* d_out, int out_size, void* d_ws, size_t ws_size,
                              hipStream_t stream) {
    const float* x   = (const float*)d_in[0];
    const int*   sid = (const int*)d_in[1];
    const float* W1  = (const float*)d_in[2];
    const float* b1  = (const float*)d_in[3];
    const float* W2  = (const float*)d_in[4];
    const float* b2  = (const float*)d_in[5];
    float* out = (float*)d_out;

    // Workspace layout: buckets | counts(32) | blockBase(NBLK1*NEXP)
    const size_t bucketBytes = (size_t)NSEG * 64 * sizeof(int);
    const size_t countBytes  = 32 * sizeof(int);
    const size_t bbBytes     = (size_t)NBLK1 * NEXP * sizeof(int);
    const size_t need = bucketBytes + countBytes + bbBytes;

    if (ws_size < need) {
        k_naive<<<(N_ROWS + 255) / 256, 256, 0, stream>>>(x, sid, W1, b1, W2, b2, out);
        return;
    }

    char* ws = (char*)d_ws;
    int* buckets   = (int*)ws;
    int* counts    = (int*)(ws + bucketBytes);
    int* blockBase = (int*)(ws + bucketBytes + countBytes);

    hipMemsetAsync(buckets, 0xFF, bucketBytes, stream);   // all -1
    hipMemsetAsync(counts, 0, countBytes, stream);
    k_hist<<<NBLK1, 256, 0, stream>>>(sid, counts, blockBase);
    k_scatter<<<NBLK1, 256, 0, stream>>>(sid, counts, blockBase, buckets);
    k_mfma<<<(NSEG + 3) / 4, 256, 0, stream>>>(x, W1, b1, W2, b2, buckets, out);
}